// Round 1
// 506.582 us; speedup vs baseline: 1.1044x; 1.1044x over previous
//
#include <hip/hip_runtime.h>
#include <hip/hip_bf16.h>
#include <math.h>

typedef __hip_bfloat16 bf16;
typedef __attribute__((ext_vector_type(8))) short s8v;   // 8 bf16 bit-carrier (4 VGPR)
typedef __attribute__((ext_vector_type(4))) float f4v;   // MFMA 16x16 accumulator

#define Bn  32
#define Cn  160
#define HWn 3136
#define Pn  100352

__device__ __forceinline__ float b2f(bf16 v){ return __bfloat162float(v); }
__device__ __forceinline__ bf16  f2b(float v){ return __float2bfloat16(v); }
__device__ __forceinline__ float bits2f(unsigned short u){
    union { float f; unsigned int i; } x; x.i = ((unsigned int)u) << 16; return x.f;
}
__device__ __forceinline__ float gelu_f(float x){ return 0.5f*x*(1.0f + erff(x*0.7071067811865476f)); }

#define MFMA(a,b,c) __builtin_amdgcn_mfma_f32_16x16x32_bf16((a),(b),(c),0,0,0)

// ---------------- K0: weight prep (fp32 -> bf16, concat/pad, LN folding) ----------------
__global__ __launch_bounds__(256) void k0_prep(
    const float* __restrict__ wt, const float* __restrict__ wb_, const float* __restrict__ wr,
    const float* __restrict__ wl, const float* __restrict__ wc,
    const float* __restrict__ bt, const float* __restrict__ bb_, const float* __restrict__ br,
    const float* __restrict__ bl, const float* __restrict__ bc,
    const float* __restrict__ wf1, const float* __restrict__ bf1,
    const float* __restrict__ g2, const float* __restrict__ b2, const float* __restrict__ m2, const float* __restrict__ v2,
    const float* __restrict__ wf2, const float* __restrict__ wfc1, const float* __restrict__ wfc2,
    const float* __restrict__ wph, const float* __restrict__ wpw,
    const float* __restrict__ lng, const float* __restrict__ lnb, const float* __restrict__ bfc1,
    bf16* wcat, bf16* wf1b, bf16* wf2b, bf16* wfc1g, bf16* wfc2b, bf16* wphb, bf16* wpwb,
    float* bcat, float* epsv, float* eptv, float* wgs, float* wcb)
{
    int idx = blockIdx.x*256 + threadIdx.x;
    if (idx < 25600){ int o = idx/160, k = idx - o*160; int gi = o>>5, oo = o&31;
        const float* wp = gi==0?wt: gi==1?wb_: gi==2?wr: gi==3?wl: wc;
        wcat[idx] = f2b(wp[oo*160+k]); return; }
    idx -= 25600;
    if (idx < 25600){ wf1b[idx] = f2b(wf1[idx]); return; }
    idx -= 25600;
    if (idx < 76800){ wf2b[idx] = f2b(wf2[idx]); return; }
    idx -= 76800;
    if (idx < 76800){ int f = idx/160, c = idx - f*160;
        wfc1g[idx] = f2b(wfc1[f*160+c] * lng[c]); return; }
    idx -= 76800;
    if (idx < 76800){ wfc2b[idx] = f2b(wfc2[idx]); return; }
    idx -= 76800;
    if (idx < 4096){ int v = idx>>6, w = idx&63;
        wphb[idx] = (v<56 && w<56) ? f2b(wph[v*56+w]) : f2b(0.f); return; }
    idx -= 4096;
    if (idx < 4096){ int v = idx>>6, w = idx&63;
        wpwb[idx] = (v<56 && w<56) ? f2b(wpw[v*56+w]) : f2b(0.f); return; }
    idx -= 4096;
    if (idx < 160){ int o = idx; int gi = o>>5, oo = o&31;
        const float* bp = gi==0?bt: gi==1?bb_: gi==2?br: gi==3?bl: bc;
        bcat[o] = bp[oo]; return; }
    idx -= 160;
    if (idx < 160){ int o = idx; float s = g2[o]*rsqrtf(v2[o]+1e-5f);
        epsv[o] = s; eptv[o] = (bf1[o]-m2[o])*s + b2[o]; return; }
    idx -= 160;
    if (idx < 480){ int o = idx; float sg = 0.f, sb = 0.f;
        const float* wr_ = wfc1 + (size_t)o*160;
        for (int c = 0; c < 160; ++c){ float w = wr_[c]; sg += w*lng[c]; sb += w*lnb[c]; }
        wgs[o] = sg; wcb[o] = sb + bfc1[o]; return; }
}

// ---------------- K1: x (NCHW fp32) -> hT = gelu(bn1(x)) (BHWC bf16) ----------------
__global__ __launch_bounds__(256) void k1_bn_gelu_tr(const float* __restrict__ x,
    const float* __restrict__ g, const float* __restrict__ b,
    const float* __restrict__ m, const float* __restrict__ v,
    bf16* __restrict__ hT)
{
    __shared__ float tile[64*161];
    __shared__ float sc[160], sh[160];
    int blk = blockIdx.x; int bb = blk/49; int hw0 = (blk - bb*49)*64;
    int tid = threadIdx.x;
    if (tid < 160){
        float s = g[tid] * rsqrtf(v[tid] + 1e-5f);
        sc[tid] = s; sh[tid] = b[tid] - m[tid]*s;
    }
    __syncthreads();
    const float* xb = x + (size_t)bb*Cn*HWn + hw0;
    for (int idx = tid; idx < 160*64; idx += 256){
        int c = idx >> 6, p = idx & 63;
        float val = xb[(size_t)c*HWn + p];
        tile[p*161 + c] = gelu_f(val*sc[c] + sh[c]);
    }
    __syncthreads();
    bf16* ho = hT + ((size_t)bb*HWn + hw0)*Cn;
    for (int idx = tid; idx < 64*160; idx += 256){
        int p = idx/160, c = idx - p*160;
        ho[idx] = f2b(tile[p*161 + c]);
    }
}

// ---------------- K2: conv5 GEMM  y5T[pos][o] = hT[pos][:] @ wcat[o][:] + bcat[o] ----------------
__global__ __launch_bounds__(256) void k2_conv5(const bf16* __restrict__ hT,
    const bf16* __restrict__ wcat, const float* __restrict__ bcat, bf16* __restrict__ y5T)
{
    __shared__ __align__(16) unsigned short Bs[2][16*168];
    int tid = threadIdx.x, wave = tid>>6, lane = tid&63, m = lane&15, q = lane>>4;
    size_t pos0 = (size_t)blockIdx.x*64;
    const unsigned short* Ap = (const unsigned short*)hT + (pos0 + wave*16 + m)*160 + q*8;
    s8v a[5];
    #pragma unroll
    for (int kb = 0; kb < 5; ++kb) a[kb] = *(const s8v*)(Ap + kb*32);
    { const s8v* sp = (const s8v*)((const unsigned short*)wcat);
      for (int c = tid; c < 320; c += 256){ int row = c/20, col = (c - row*20)*8;
          *(s8v*)&Bs[0][row*168 + col] = sp[c]; } }
    __syncthreads();
    for (int s = 0; s < 10; ++s){
        if (s+1 < 10){
            const s8v* sp = (const s8v*)((const unsigned short*)wcat + (size_t)(s+1)*2560);
            for (int c = tid; c < 320; c += 256){ int row = c/20, col = (c - row*20)*8;
                *(s8v*)&Bs[(s+1)&1][row*168 + col] = sp[c]; }
        }
        f4v acc = {0.f,0.f,0.f,0.f};
        const unsigned short* Bp = &Bs[s&1][m*168 + q*8];
        #pragma unroll
        for (int kb = 0; kb < 5; ++kb) acc = MFMA(a[kb], *(const s8v*)(Bp + kb*32), acc);
        float bias = bcat[s*16 + m];
        bf16* yo = y5T + (pos0 + wave*16 + q*4)*160 + s*16 + m;
        #pragma unroll
        for (int r = 0; r < 4; ++r) yo[r*160] = f2b(acc[r] + bias);
        __syncthreads();
    }
}

// ---------------- K3: shifted-A GEMM + bn2 + gelu -> gT ----------------
__global__ __launch_bounds__(256) void k3_wf1(const bf16* __restrict__ y5T,
    const bf16* __restrict__ wf1b, const float* __restrict__ epsv, const float* __restrict__ eptv,
    bf16* __restrict__ gT)
{
    __shared__ __align__(16) unsigned short Bs[2][16*168];
    int tid = threadIdx.x, wave = tid>>6, lane = tid&63, m = lane&15, q = lane>>4;
    int blk = blockIdx.x; int bb = blk/49; int hw0 = (blk - bb*49)*64;
    size_t pos0 = (size_t)bb*HWn + hw0;
    int phw = hw0 + wave*16 + m; int h = phw/56, w = phw - h*56;
    s8v a[5];
    #pragma unroll
    for (int kb = 0; kb < 5; ++kb){
        int h2 = h, w2 = w; bool ok = true;
        if      (kb == 0){ h2 = h+1; ok = (h2 < 56); }
        else if (kb == 1){ h2 = h-1; ok = (h2 >= 0); }
        else if (kb == 2){ w2 = w-1; ok = (w2 >= 0); }
        else if (kb == 3){ w2 = w+1; ok = (w2 < 56); }
        if (ok){
            const unsigned short* Ap = (const unsigned short*)y5T +
                ((size_t)bb*HWn + h2*56 + w2)*160 + kb*32 + q*8;
            a[kb] = *(const s8v*)Ap;
        } else {
            a[kb] = (s8v){0,0,0,0,0,0,0,0};
        }
    }
    { const s8v* sp = (const s8v*)((const unsigned short*)wf1b);
      for (int c = tid; c < 320; c += 256){ int row = c/20, col = (c - row*20)*8;
          *(s8v*)&Bs[0][row*168 + col] = sp[c]; } }
    __syncthreads();
    for (int s = 0; s < 10; ++s){
        if (s+1 < 10){
            const s8v* sp = (const s8v*)((const unsigned short*)wf1b + (size_t)(s+1)*2560);
            for (int c = tid; c < 320; c += 256){ int row = c/20, col = (c - row*20)*8;
                *(s8v*)&Bs[(s+1)&1][row*168 + col] = sp[c]; }
        }
        f4v acc = {0.f,0.f,0.f,0.f};
        const unsigned short* Bp = &Bs[s&1][m*168 + q*8];
        #pragma unroll
        for (int kb = 0; kb < 5; ++kb) acc = MFMA(a[kb], *(const s8v*)(Bp + kb*32), acc);
        int o = s*16 + m;
        float es = epsv[o], et = eptv[o];
        bf16* go = gT + (pos0 + wave*16 + q*4)*160 + o;
        #pragma unroll
        for (int r = 0; r < 4; ++r) go[r*160] = f2b(gelu_f(acc[r]*es + et));
        __syncthreads();
    }
}

// ---------------- K4: proj_h MFMA ----------------
__global__ __launch_bounds__(256) void k4_projh(const bf16* __restrict__ gT,
    const bf16* __restrict__ wphb, const float* __restrict__ bph, bf16* __restrict__ xhT)
{
    __shared__ __align__(16) unsigned short gS[160*72];
    int tid = threadIdx.x, wave = tid>>6, lane = tid&63, m = lane&15, q = lane>>4;
    int blk = blockIdx.x; int b = blk/56, h = blk - b*56;
    const unsigned short* ga = (const unsigned short*)gT + ((size_t)b*HWn + h*56)*160;
    for (int idx = tid; idx < 56*160; idx += 256){
        int w = idx/160, c = idx - w*160;
        gS[c*72 + w] = ga[idx];
    }
    for (int idx = tid; idx < 160*8; idx += 256){
        int c = idx>>3, w = 56 + (idx&7);
        gS[c*72 + w] = 0;
    }
    __syncthreads();
    int v0 = wave*16;
    s8v a[2];
    #pragma unroll
    for (int kb = 0; kb < 2; ++kb)
        a[kb] = *(const s8v*)((const unsigned short*)wphb + (v0+m)*64 + kb*32 + q*8);
    int v = v0 + q*4;
    for (int s = 0; s < 10; ++s){
        f4v acc = {0.f,0.f,0.f,0.f};
        const unsigned short* Bp = &gS[(s*16+m)*72 + q*8];
        #pragma unroll
        for (int kb = 0; kb < 2; ++kb) acc = MFMA(a[kb], *(const s8v*)(Bp + kb*32), acc);
        #pragma unroll
        for (int r = 0; r < 4; ++r){
            int vv = v + r;
            if (vv < 56)
                xhT[((size_t)b*HWn + h*56 + vv)*160 + s*16 + m] = f2b(acc[r] + bph[vv]);
        }
    }
}

// ---------------- K5: proj_w MFMA ----------------
__global__ __launch_bounds__(256) void k5_projw(const bf16* __restrict__ gT,
    const bf16* __restrict__ wpwb, const float* __restrict__ bpw, bf16* __restrict__ xwT)
{
    __shared__ __align__(16) unsigned short gS[160*72];
    int tid = threadIdx.x, wave = tid>>6, lane = tid&63, m = lane&15, q = lane>>4;
    int blk = blockIdx.x; int b = blk/56, w = blk - b*56;
    const unsigned short* gbase = (const unsigned short*)gT + ((size_t)b*HWn + w)*160;
    for (int idx = tid; idx < 56*160; idx += 256){
        int hh = idx/160, c = idx - hh*160;
        gS[c*72 + hh] = gbase[(size_t)hh*56*160 + c];
    }
    for (int idx = tid; idx < 160*8; idx += 256){
        int c = idx>>3, hh = 56 + (idx&7);
        gS[c*72 + hh] = 0;
    }
    __syncthreads();
    int v0 = wave*16;
    s8v a[2];
    #pragma unroll
    for (int kb = 0; kb < 2; ++kb)
        a[kb] = *(const s8v*)((const unsigned short*)wpwb + (v0+m)*64 + kb*32 + q*8);
    int v = v0 + q*4;
    for (int s = 0; s < 10; ++s){
        f4v acc = {0.f,0.f,0.f,0.f};
        const unsigned short* Bp = &gS[(s*16+m)*72 + q*8];
        #pragma unroll
        for (int kb = 0; kb < 2; ++kb) acc = MFMA(a[kb], *(const s8v*)(Bp + kb*32), acc);
        #pragma unroll
        for (int r = 0; r < 4; ++r){
            int vv = v + r;
            if (vv < 56)
                xwT[((size_t)b*HWn + vv*56 + w)*160 + s*16 + m] = f2b(acc[r] + bpw[vv]);
        }
    }
}

// ---------------- K6: wf2 GEMM (K=480 concat) -> gm bf16 BHWC ----------------
__global__ __launch_bounds__(256) void k6_wf2(const bf16* __restrict__ gT,
    const bf16* __restrict__ xhT, const bf16* __restrict__ xwT,
    const bf16* __restrict__ wf2b, bf16* __restrict__ gm)
{
    __shared__ __align__(16) unsigned short Bs[2][16*488];
    int tid = threadIdx.x, wave = tid>>6, lane = tid&63, m = lane&15, q = lane>>4;
    size_t pos0 = (size_t)blockIdx.x*64;
    size_t prow = (pos0 + wave*16 + m)*160;
    s8v a[15];
    #pragma unroll
    for (int kb = 0; kb < 15; ++kb){
        const bf16* src = (kb < 5) ? gT : (kb < 10 ? xhT : xwT);
        int kc = (kb - (kb < 5 ? 0 : (kb < 10 ? 5 : 10)))*32 + q*8;
        a[kb] = *(const s8v*)((const unsigned short*)src + prow + kc);
    }
    { const s8v* sp = (const s8v*)((const unsigned short*)wf2b);
      for (int c = tid; c < 960; c += 256){ int row = c/60, col = (c - row*60)*8;
          *(s8v*)&Bs[0][row*488 + col] = sp[c]; } }
    __syncthreads();
    for (int s = 0; s < 10; ++s){
        if (s+1 < 10){
            const s8v* sp = (const s8v*)((const unsigned short*)wf2b + (size_t)(s+1)*7680);
            for (int c = tid; c < 960; c += 256){ int row = c/60, col = (c - row*60)*8;
                *(s8v*)&Bs[(s+1)&1][row*488 + col] = sp[c]; }
        }
        f4v acc = {0.f,0.f,0.f,0.f};
        const unsigned short* Bp = &Bs[s&1][m*488 + q*8];
        #pragma unroll
        for (int kb = 0; kb < 15; ++kb) acc = MFMA(a[kb], *(const s8v*)(Bp + kb*32), acc);
        bf16* go = gm + (pos0 + wave*16 + q*4)*160 + s*16 + m;
        #pragma unroll
        for (int r = 0; r < 4; ++r) go[r*160] = f2b(acc[r]);
        __syncthreads();
    }
}

// ---------------- K7: LN folded into fc1 GEMM; barrier-free main loop ----------------
// out[p][f] = gelu( rstd_p * (Wg @ y)[p][f] + (-mu_p*rstd_p)*wgs[f] + wcb[f] )
// where y = x + gm (raw, un-normalized), Wg = wfc1 * ln_g (per-column).
__global__ __launch_bounds__(256,4) void k7_ln_fc1(const float* __restrict__ x,
    const bf16* __restrict__ gm,
    const bf16* __restrict__ wfc1g, const float* __restrict__ wgs, const float* __restrict__ wcb,
    bf16* __restrict__ u)
{
    // 40960 B exactly -> 4 blocks/CU. Union: fp32 x-tile [160][64], then bf16 y [64][160]
    // (20480 B) + rstd/mrs (64+64 floats at byte 20480/20736).
    __shared__ __align__(16) float XsU[160*64];
    unsigned short* As = (unsigned short*)XsU;
    float* rstd_s = XsU + 5120;
    float* mrs_s  = XsU + 5184;
    int tid = threadIdx.x, wave = tid>>6, lane = tid&63, m = lane&15, q = lane>>4;
    int blk = blockIdx.x; int bb = blk/49; int hw0 = (blk - bb*49)*64;
    size_t pos0 = (size_t)bb*HWn + hw0;
    const float* xb = x + (size_t)bb*Cn*HWn + hw0;
    // stage 1: transpose x into LDS (fp32), layout [c][p] -> contiguous, conflict-free
    for (int idx = tid; idx < 160*64; idx += 256){
        int c = idx >> 6, p = idx & 63;
        XsU[idx] = xb[(size_t)c*HWn + p];
    }
    __syncthreads();
    // stage 2: y = x + gm into registers, per-position mean/var (4 threads x 40 ch)
    int p = tid >> 2, q4 = tid & 3;
    {
        const s8v* gp = (const s8v*)((const unsigned short*)gm + (pos0 + p)*160 + q4*40);
        float y[40];
        float s = 0.f, ss = 0.f;
        #pragma unroll
        for (int j = 0; j < 5; ++j){
            s8v gv = gp[j];
            #pragma unroll
            for (int t = 0; t < 8; ++t){
                int i = j*8 + t;
                float vv = XsU[(q4*40 + i)*64 + p] + bits2f((unsigned short)gv[t]);
                y[i] = vv; s += vv; ss += vv*vv;
            }
        }
        s  += __shfl_xor(s, 1);  ss += __shfl_xor(ss, 1);
        s  += __shfl_xor(s, 2);  ss += __shfl_xor(ss, 2);
        float mean = s * (1.f/160.f);
        float var  = ss * (1.f/160.f) - mean*mean;
        float rstd = rsqrtf(var + 1e-5f);
        __syncthreads();   // all fp32 reads of XsU complete before overwrite
        #pragma unroll
        for (int j = 0; j < 5; ++j){
            s8v pk;
            #pragma unroll
            for (int t = 0; t < 8; ++t){
                union { unsigned short us; bf16 b; } cv; cv.b = f2b(y[j*8 + t]);
                pk[t] = (short)cv.us;
            }
            *(s8v*)&As[p*160 + q4*40 + j*8] = pk;
        }
        if (q4 == 0){ rstd_s[p] = rstd; mrs_s[p] = -mean*rstd; }
    }
    __syncthreads();
    // A fragments (read once), per-row LN scalars (hoisted)
    s8v a[5];
    const unsigned short* Ap = &As[(wave*16 + m)*160 + q*8];
    #pragma unroll
    for (int kb = 0; kb < 5; ++kb) a[kb] = *(const s8v*)(Ap + kb*32);
    float rst[4], mrs[4];
    #pragma unroll
    for (int r = 0; r < 4; ++r){
        rst[r] = rstd_s[wave*16 + q*4 + r];
        mrs[r] = mrs_s [wave*16 + q*4 + r];
    }
    // barrier-free GEMM: B fragments direct from global (L2-hot), reg double-buffered
    const unsigned short* Wp = (const unsigned short*)wfc1g + (size_t)m*160 + q*8;
    bf16* uo = u + (pos0 + wave*16 + q*4)*480 + m;
    s8v b0[5], b1[5];
    #pragma unroll
    for (int kb = 0; kb < 5; ++kb) b0[kb] = *(const s8v*)(Wp + kb*32);
    for (int s = 0; s < 30; s += 2){
        {
            const unsigned short* Wn = Wp + (size_t)(s+1)*2560;
            #pragma unroll
            for (int kb = 0; kb < 5; ++kb) b1[kb] = *(const s8v*)(Wn + kb*32);
        }
        f4v acc = {0.f,0.f,0.f,0.f};
        #pragma unroll
        for (int kb = 0; kb < 5; ++kb) acc = MFMA(a[kb], b0[kb], acc);
        {
            int o = s*16 + m; float wg = wgs[o], wc = wcb[o];
            #pragma unroll
            for (int r = 0; r < 4; ++r){
                float v = acc[r]*rst[r] + mrs[r]*wg + wc;
                uo[(size_t)r*480 + s*16] = f2b(gelu_f(v));
            }
        }
        if (s + 2 < 30){
            const unsigned short* Wn = Wp + (size_t)(s+2)*2560;
            #pragma unroll
            for (int kb = 0; kb < 5; ++kb) b0[kb] = *(const s8v*)(Wn + kb*32);
        }
        f4v acc2 = {0.f,0.f,0.f,0.f};
        #pragma unroll
        for (int kb = 0; kb < 5; ++kb) acc2 = MFMA(a[kb], b1[kb], acc2);
        {
            int o = (s+1)*16 + m; float wg = wgs[o], wc = wcb[o];
            #pragma unroll
            for (int r = 0; r < 4; ++r){
                float v = acc2[r]*rst[r] + mrs[r]*wg + wc;
                uo[(size_t)r*480 + (s+1)*16] = f2b(gelu_f(v));
            }
        }
    }
}

// ---------------- K8: fc2 (K=480) + bfc2 + (x+gm) residual -> out NCHW fp32 ----------------
__global__ __launch_bounds__(256) void k8_fc2(const bf16* __restrict__ u,
    const bf16* __restrict__ wfc2b, const float* __restrict__ bfc2,
    const float* __restrict__ x, const bf16* __restrict__ gm, float* __restrict__ out)
{
    __shared__ float Ds[64*161];
    __shared__ __align__(16) unsigned short Bs[2][16*488];
    int tid = threadIdx.x, wave = tid>>6, lane = tid&63, m = lane&15, q = lane>>4;
    int blk = blockIdx.x; int bb = blk/49; int hw0 = (blk - bb*49)*64;
    size_t pos0 = (size_t)bb*HWn + hw0;
    const float* xb = x + (size_t)bb*Cn*HWn + hw0;
    for (int idx = tid; idx < 160*64; idx += 256){
        int o = idx >> 6, p = idx & 63;
        Ds[p*161 + o] = xb[(size_t)o*HWn + p];
    }
    { const s8v* sp = (const s8v*)((const unsigned short*)wfc2b);
      for (int c = tid; c < 960; c += 256){ int row = c/60, col = (c - row*60)*8;
          *(s8v*)&Bs[0][row*488 + col] = sp[c]; } }
    __syncthreads();
    {
        const unsigned short* gp = (const unsigned short*)gm + pos0*160;
        for (int idx = tid; idx < 64*160; idx += 256){
            int p = idx/160, c = idx - p*160;
            Ds[p*161 + c] += bits2f(gp[idx]);
        }
    }
    __syncthreads();
    const unsigned short* Ap = (const unsigned short*)u + (pos0 + wave*16 + m)*480 + q*8;
    s8v a[15];
    #pragma unroll
    for (int kb = 0; kb < 15; ++kb) a[kb] = *(const s8v*)(Ap + kb*32);
    for (int s = 0; s < 10; ++s){
        if (s+1 < 10){
            const s8v* sp = (const s8v*)((const unsigned short*)wfc2b + (size_t)(s+1)*7680);
            for (int c = tid; c < 960; c += 256){ int row = c/60, col = (c - row*60)*8;
                *(s8v*)&Bs[(s+1)&1][row*488 + col] = sp[c]; }
        }
        f4v acc = {0.f,0.f,0.f,0.f};
        const unsigned short* Bp = &Bs[s&1][m*488 + q*8];
        #pragma unroll
        for (int kb = 0; kb < 15; ++kb) acc = MFMA(a[kb], *(const s8v*)(Bp + kb*32), acc);
        int o = s*16 + m; float bias = bfc2[o];
        #pragma unroll
        for (int r = 0; r < 4; ++r)
            Ds[(wave*16 + q*4 + r)*161 + o] += acc[r] + bias;
        __syncthreads();
    }
    float* ob = out + (size_t)bb*Cn*HWn + hw0;
    for (int idx = tid; idx < 160*64; idx += 256){
        int o = idx >> 6, p = idx & 63;
        ob[(size_t)o*HWn + p] = Ds[p*161 + o];
    }
}

extern "C" void kernel_launch(void* const* d_in, const int* in_sizes, int n_in,
                              void* d_out, int out_size, void* d_ws, size_t ws_size,
                              hipStream_t stream)
{
    (void)in_sizes; (void)n_in; (void)out_size; (void)ws_size;
    const float* x     = (const float*)d_in[0];
    const float* bn1g  = (const float*)d_in[1];
    const float* bn1b  = (const float*)d_in[2];
    const float* bn1m  = (const float*)d_in[3];
    const float* bn1v  = (const float*)d_in[4];
    const float* wt    = (const float*)d_in[5];
    const float* bt    = (const float*)d_in[6];
    const float* wb    = (const float*)d_in[7];
    const float* bb    = (const float*)d_in[8];
    const float* wr    = (const float*)d_in[9];
    const float* br    = (const float*)d_in[10];
    const float* wl    = (const float*)d_in[11];
    const float* bl    = (const float*)d_in[12];
    const float* wc    = (const float*)d_in[13];
    const float* bc    = (const float*)d_in[14];
    const float* wf1   = (const float*)d_in[15];
    const float* bf1   = (const float*)d_in[16];
    const float* bn2g  = (const float*)d_in[17];
    const float* bn2b  = (const float*)d_in[18];
    const float* bn2m  = (const float*)d_in[19];
    const float* bn2v  = (const float*)d_in[20];
    const float* wph   = (const float*)d_in[21];
    const float* bph   = (const float*)d_in[22];
    const float* wpw   = (const float*)d_in[23];
    const float* bpw   = (const float*)d_in[24];
    const float* wf2   = (const float*)d_in[25];
    const float* lng   = (const float*)d_in[26];
    const float* lnb   = (const float*)d_in[27];
    const float* wfc1  = (const float*)d_in[28];
    const float* bfc1  = (const float*)d_in[29];
    const float* wfc2  = (const float*)d_in[30];
    const float* bfc2v = (const float*)d_in[31];
    float* outp = (float*)d_out;

    // workspace layout (bytes); bf16 [Pn][160] buffer = 32,112,640 B
    const size_t PC2 = (size_t)Pn*160*2;
    char* ws = (char*)d_ws;
    bf16* hT   = (bf16*)(ws + 0*PC2);
    bf16* y5T  = (bf16*)(ws + 1*PC2);
    bf16* gT   = (bf16*)(ws + 2*PC2);
    bf16* xhT  = (bf16*)(ws + 3*PC2);
    bf16* xwT  = (bf16*)(ws + 4*PC2);
    bf16* gm   = (bf16*)(ws + 5*PC2);
    char* wsw  = ws + 6*PC2;                       // weights @ 192,675,840
    bf16*  wcat  = (bf16*)(wsw + 0);
    bf16*  wf1b  = (bf16*)(wsw + 51200);
    bf16*  wf2b  = (bf16*)(wsw + 102400);
    bf16*  wfc1g = (bf16*)(wsw + 256000);
    bf16*  wfc2b = (bf16*)(wsw + 409600);
    bf16*  wphb  = (bf16*)(wsw + 563200);
    bf16*  wpwb  = (bf16*)(wsw + 571392);
    float* bcat  = (float*)(wsw + 579584);
    float* epsv  = (float*)(wsw + 580224);
    float* eptv  = (float*)(wsw + 580864);
    float* wgs   = (float*)(wsw + 581504);
    float* wcb   = (float*)(wsw + 583424);
    bf16* uB   = (bf16*)(ws + 0);                  // [Pn][480] bf16, reuses hT/y5T/gT (dead by k7)

    const int GP = Pn/64;     // 1568
    const int GS = Bn*56;     // 1792

    k0_prep<<<1136, 256, 0, stream>>>(wt, wb, wr, wl, wc, bt, bb, br, bl, bc,
                                      wf1, bf1, bn2g, bn2b, bn2m, bn2v,
                                      wf2, wfc1, wfc2, wph, wpw,
                                      lng, lnb, bfc1,
                                      wcat, wf1b, wf2b, wfc1g, wfc2b, wphb, wpwb,
                                      bcat, epsv, eptv, wgs, wcb);
    k1_bn_gelu_tr<<<GP, 256, 0, stream>>>(x, bn1g, bn1b, bn1m, bn1v, hT);
    k2_conv5     <<<GP, 256, 0, stream>>>(hT, wcat, bcat, y5T);
    k3_wf1       <<<GP, 256, 0, stream>>>(y5T, wf1b, epsv, eptv, gT);
    k4_projh     <<<GS, 256, 0, stream>>>(gT, wphb, bph, xhT);
    k5_projw     <<<GS, 256, 0, stream>>>(gT, wpwb, bpw, xwT);
    k6_wf2       <<<GP, 256, 0, stream>>>(gT, xhT, xwT, wf2b, gm);
    k7_ln_fc1    <<<GP, 256, 0, stream>>>(x, gm, wfc1g, wgs, wcb, uB);
    k8_fc2       <<<GP, 256, 0, stream>>>(uB, wfc2b, bfc2v, x, gm, outp);
}

// Round 2
// 478.061 us; speedup vs baseline: 1.1703x; 1.0597x over previous
//
#include <hip/hip_runtime.h>
#include <hip/hip_bf16.h>
#include <math.h>

typedef __hip_bfloat16 bf16;
typedef __attribute__((ext_vector_type(8))) short s8v;   // 8 bf16 bit-carrier (4 VGPR)
typedef __attribute__((ext_vector_type(4))) float f4v;   // MFMA 16x16 accumulator / float4
typedef __attribute__((ext_vector_type(4))) unsigned short u4v; // 8B bf16 carrier

#define Bn  32
#define Cn  160
#define HWn 3136
#define Pn  100352

__device__ __forceinline__ float b2f(bf16 v){ return __bfloat162float(v); }
__device__ __forceinline__ bf16  f2b(float v){ return __float2bfloat16(v); }
__device__ __forceinline__ float bits2f(unsigned short u){
    union { float f; unsigned int i; } x; x.i = ((unsigned int)u) << 16; return x.f;
}
__device__ __forceinline__ unsigned short f2bits(float v){
    union { unsigned short us; bf16 b; } cv; cv.b = f2b(v); return cv.us;
}
__device__ __forceinline__ float gelu_f(float x){ return 0.5f*x*(1.0f + erff(x*0.7071067811865476f)); }

#define MFMA(a,b,c) __builtin_amdgcn_mfma_f32_16x16x32_bf16((a),(b),(c),0,0,0)

// ---------------- K0: weight prep (fp32 -> bf16, concat/pad, LN folding) ----------------
__global__ __launch_bounds__(256) void k0_prep(
    const float* __restrict__ wt, const float* __restrict__ wb_, const float* __restrict__ wr,
    const float* __restrict__ wl, const float* __restrict__ wc,
    const float* __restrict__ bt, const float* __restrict__ bb_, const float* __restrict__ br,
    const float* __restrict__ bl, const float* __restrict__ bc,
    const float* __restrict__ wf1, const float* __restrict__ bf1,
    const float* __restrict__ g2, const float* __restrict__ b2, const float* __restrict__ m2, const float* __restrict__ v2,
    const float* __restrict__ wf2, const float* __restrict__ wfc1, const float* __restrict__ wfc2,
    const float* __restrict__ wph, const float* __restrict__ wpw,
    const float* __restrict__ lng, const float* __restrict__ lnb, const float* __restrict__ bfc1,
    bf16* wcat, bf16* wf1b, bf16* wf2b, bf16* wfc1g, bf16* wfc2b, bf16* wphb, bf16* wpwb,
    float* bcat, float* epsv, float* eptv, float* wgs, float* wcb)
{
    int idx = blockIdx.x*256 + threadIdx.x;
    if (idx < 25600){ int o = idx/160, k = idx - o*160; int gi = o>>5, oo = o&31;
        const float* wp = gi==0?wt: gi==1?wb_: gi==2?wr: gi==3?wl: wc;
        wcat[idx] = f2b(wp[oo*160+k]); return; }
    idx -= 25600;
    if (idx < 25600){ wf1b[idx] = f2b(wf1[idx]); return; }
    idx -= 25600;
    if (idx < 76800){ wf2b[idx] = f2b(wf2[idx]); return; }
    idx -= 76800;
    if (idx < 76800){ int f = idx/160, c = idx - f*160;
        wfc1g[idx] = f2b(wfc1[f*160+c] * lng[c]); return; }
    idx -= 76800;
    if (idx < 76800){ wfc2b[idx] = f2b(wfc2[idx]); return; }
    idx -= 76800;
    if (idx < 4096){ int v = idx>>6, w = idx&63;
        wphb[idx] = (v<56 && w<56) ? f2b(wph[v*56+w]) : f2b(0.f); return; }
    idx -= 4096;
    if (idx < 4096){ int v = idx>>6, w = idx&63;
        wpwb[idx] = (v<56 && w<56) ? f2b(wpw[v*56+w]) : f2b(0.f); return; }
    idx -= 4096;
    if (idx < 160){ int o = idx; int gi = o>>5, oo = o&31;
        const float* bp = gi==0?bt: gi==1?bb_: gi==2?br: gi==3?bl: bc;
        bcat[o] = bp[oo]; return; }
    idx -= 160;
    if (idx < 160){ int o = idx; float s = g2[o]*rsqrtf(v2[o]+1e-5f);
        epsv[o] = s; eptv[o] = (bf1[o]-m2[o])*s + b2[o]; return; }
    idx -= 160;
    if (idx < 480){ int o = idx; float sg = 0.f, sb = 0.f;
        const float* wr_ = wfc1 + (size_t)o*160;
        for (int c = 0; c < 160; ++c){ float w = wr_[c]; sg += w*lng[c]; sb += w*lnb[c]; }
        wgs[o] = sg; wcb[o] = sb + bfc1[o]; return; }
}

// ---------------- K1: x (NCHW fp32) -> hT = gelu(bn1(x)) (BHWC bf16) ----------------
__global__ __launch_bounds__(256) void k1_bn_gelu_tr(const float* __restrict__ x,
    const float* __restrict__ g, const float* __restrict__ b,
    const float* __restrict__ m, const float* __restrict__ v,
    bf16* __restrict__ hT)
{
    __shared__ float tile[64*161];
    __shared__ float sc[160], sh[160];
    int blk = blockIdx.x; int bb = blk/49; int hw0 = (blk - bb*49)*64;
    int tid = threadIdx.x;
    if (tid < 160){
        float s = g[tid] * rsqrtf(v[tid] + 1e-5f);
        sc[tid] = s; sh[tid] = b[tid] - m[tid]*s;
    }
    __syncthreads();
    const float* xb = x + (size_t)bb*Cn*HWn + hw0;
    for (int idx = tid; idx < 160*64; idx += 256){
        int c = idx >> 6, p = idx & 63;
        float val = xb[(size_t)c*HWn + p];
        tile[p*161 + c] = gelu_f(val*sc[c] + sh[c]);
    }
    __syncthreads();
    bf16* ho = hT + ((size_t)bb*HWn + hw0)*Cn;
    for (int idx = tid; idx < 64*160; idx += 256){
        int p = idx/160, c = idx - p*160;
        ho[idx] = f2b(tile[p*161 + c]);
    }
}

// ---------------- K2: conv5 GEMM  y5T[pos][o] = hT[pos][:] @ wcat[o][:] + bcat[o] ----------------
__global__ __launch_bounds__(256) void k2_conv5(const bf16* __restrict__ hT,
    const bf16* __restrict__ wcat, const float* __restrict__ bcat, bf16* __restrict__ y5T)
{
    __shared__ __align__(16) unsigned short Bs[2][16*168];
    int tid = threadIdx.x, wave = tid>>6, lane = tid&63, m = lane&15, q = lane>>4;
    size_t pos0 = (size_t)blockIdx.x*64;
    const unsigned short* Ap = (const unsigned short*)hT + (pos0 + wave*16 + m)*160 + q*8;
    s8v a[5];
    #pragma unroll
    for (int kb = 0; kb < 5; ++kb) a[kb] = *(const s8v*)(Ap + kb*32);
    { const s8v* sp = (const s8v*)((const unsigned short*)wcat);
      for (int c = tid; c < 320; c += 256){ int row = c/20, col = (c - row*20)*8;
          *(s8v*)&Bs[0][row*168 + col] = sp[c]; } }
    __syncthreads();
    for (int s = 0; s < 10; ++s){
        if (s+1 < 10){
            const s8v* sp = (const s8v*)((const unsigned short*)wcat + (size_t)(s+1)*2560);
            for (int c = tid; c < 320; c += 256){ int row = c/20, col = (c - row*20)*8;
                *(s8v*)&Bs[(s+1)&1][row*168 + col] = sp[c]; }
        }
        f4v acc = {0.f,0.f,0.f,0.f};
        const unsigned short* Bp = &Bs[s&1][m*168 + q*8];
        #pragma unroll
        for (int kb = 0; kb < 5; ++kb) acc = MFMA(a[kb], *(const s8v*)(Bp + kb*32), acc);
        float bias = bcat[s*16 + m];
        bf16* yo = y5T + (pos0 + wave*16 + q*4)*160 + s*16 + m;
        #pragma unroll
        for (int r = 0; r < 4; ++r) yo[r*160] = f2b(acc[r] + bias);
        __syncthreads();
    }
}

// ---------------- K3: shifted-A GEMM + bn2 + gelu -> gT ----------------
__global__ __launch_bounds__(256) void k3_wf1(const bf16* __restrict__ y5T,
    const bf16* __restrict__ wf1b, const float* __restrict__ epsv, const float* __restrict__ eptv,
    bf16* __restrict__ gT)
{
    __shared__ __align__(16) unsigned short Bs[2][16*168];
    int tid = threadIdx.x, wave = tid>>6, lane = tid&63, m = lane&15, q = lane>>4;
    int blk = blockIdx.x; int bb = blk/49; int hw0 = (blk - bb*49)*64;
    size_t pos0 = (size_t)bb*HWn + hw0;
    int phw = hw0 + wave*16 + m; int h = phw/56, w = phw - h*56;
    s8v a[5];
    #pragma unroll
    for (int kb = 0; kb < 5; ++kb){
        int h2 = h, w2 = w; bool ok = true;
        if      (kb == 0){ h2 = h+1; ok = (h2 < 56); }
        else if (kb == 1){ h2 = h-1; ok = (h2 >= 0); }
        else if (kb == 2){ w2 = w-1; ok = (w2 >= 0); }
        else if (kb == 3){ w2 = w+1; ok = (w2 < 56); }
        if (ok){
            const unsigned short* Ap = (const unsigned short*)y5T +
                ((size_t)bb*HWn + h2*56 + w2)*160 + kb*32 + q*8;
            a[kb] = *(const s8v*)Ap;
        } else {
            a[kb] = (s8v){0,0,0,0,0,0,0,0};
        }
    }
    { const s8v* sp = (const s8v*)((const unsigned short*)wf1b);
      for (int c = tid; c < 320; c += 256){ int row = c/20, col = (c - row*20)*8;
          *(s8v*)&Bs[0][row*168 + col] = sp[c]; } }
    __syncthreads();
    for (int s = 0; s < 10; ++s){
        if (s+1 < 10){
            const s8v* sp = (const s8v*)((const unsigned short*)wf1b + (size_t)(s+1)*2560);
            for (int c = tid; c < 320; c += 256){ int row = c/20, col = (c - row*20)*8;
                *(s8v*)&Bs[(s+1)&1][row*168 + col] = sp[c]; }
        }
        f4v acc = {0.f,0.f,0.f,0.f};
        const unsigned short* Bp = &Bs[s&1][m*168 + q*8];
        #pragma unroll
        for (int kb = 0; kb < 5; ++kb) acc = MFMA(a[kb], *(const s8v*)(Bp + kb*32), acc);
        int o = s*16 + m;
        float es = epsv[o], et = eptv[o];
        bf16* go = gT + (pos0 + wave*16 + q*4)*160 + o;
        #pragma unroll
        for (int r = 0; r < 4; ++r) go[r*160] = f2b(gelu_f(acc[r]*es + et));
        __syncthreads();
    }
}

// ---------------- K4: proj_h MFMA ----------------
__global__ __launch_bounds__(256) void k4_projh(const bf16* __restrict__ gT,
    const bf16* __restrict__ wphb, const float* __restrict__ bph, bf16* __restrict__ xhT)
{
    __shared__ __align__(16) unsigned short gS[160*72];
    int tid = threadIdx.x, wave = tid>>6, lane = tid&63, m = lane&15, q = lane>>4;
    int blk = blockIdx.x; int b = blk/56, h = blk - b*56;
    const unsigned short* ga = (const unsigned short*)gT + ((size_t)b*HWn + h*56)*160;
    for (int idx = tid; idx < 56*160; idx += 256){
        int w = idx/160, c = idx - w*160;
        gS[c*72 + w] = ga[idx];
    }
    for (int idx = tid; idx < 160*8; idx += 256){
        int c = idx>>3, w = 56 + (idx&7);
        gS[c*72 + w] = 0;
    }
    __syncthreads();
    int v0 = wave*16;
    s8v a[2];
    #pragma unroll
    for (int kb = 0; kb < 2; ++kb)
        a[kb] = *(const s8v*)((const unsigned short*)wphb + (v0+m)*64 + kb*32 + q*8);
    int v = v0 + q*4;
    for (int s = 0; s < 10; ++s){
        f4v acc = {0.f,0.f,0.f,0.f};
        const unsigned short* Bp = &gS[(s*16+m)*72 + q*8];
        #pragma unroll
        for (int kb = 0; kb < 2; ++kb) acc = MFMA(a[kb], *(const s8v*)(Bp + kb*32), acc);
        #pragma unroll
        for (int r = 0; r < 4; ++r){
            int vv = v + r;
            if (vv < 56)
                xhT[((size_t)b*HWn + h*56 + vv)*160 + s*16 + m] = f2b(acc[r] + bph[vv]);
        }
    }
}

// ---------------- K5: proj_w MFMA ----------------
__global__ __launch_bounds__(256) void k5_projw(const bf16* __restrict__ gT,
    const bf16* __restrict__ wpwb, const float* __restrict__ bpw, bf16* __restrict__ xwT)
{
    __shared__ __align__(16) unsigned short gS[160*72];
    int tid = threadIdx.x, wave = tid>>6, lane = tid&63, m = lane&15, q = lane>>4;
    int blk = blockIdx.x; int b = blk/56, w = blk - b*56;
    const unsigned short* gbase = (const unsigned short*)gT + ((size_t)b*HWn + w)*160;
    for (int idx = tid; idx < 56*160; idx += 256){
        int hh = idx/160, c = idx - hh*160;
        gS[c*72 + hh] = gbase[(size_t)hh*56*160 + c];
    }
    for (int idx = tid; idx < 160*8; idx += 256){
        int c = idx>>3, hh = 56 + (idx&7);
        gS[c*72 + hh] = 0;
    }
    __syncthreads();
    int v0 = wave*16;
    s8v a[2];
    #pragma unroll
    for (int kb = 0; kb < 2; ++kb)
        a[kb] = *(const s8v*)((const unsigned short*)wpwb + (v0+m)*64 + kb*32 + q*8);
    int v = v0 + q*4;
    for (int s = 0; s < 10; ++s){
        f4v acc = {0.f,0.f,0.f,0.f};
        const unsigned short* Bp = &gS[(s*16+m)*72 + q*8];
        #pragma unroll
        for (int kb = 0; kb < 2; ++kb) acc = MFMA(a[kb], *(const s8v*)(Bp + kb*32), acc);
        #pragma unroll
        for (int r = 0; r < 4; ++r){
            int vv = v + r;
            if (vv < 56)
                xwT[((size_t)b*HWn + vv*56 + w)*160 + s*16 + m] = f2b(acc[r] + bpw[vv]);
        }
    }
}

// ---------------- K6: wf2 GEMM (K=480 concat) -> gm bf16 BHWC ----------------
__global__ __launch_bounds__(256) void k6_wf2(const bf16* __restrict__ gT,
    const bf16* __restrict__ xhT, const bf16* __restrict__ xwT,
    const bf16* __restrict__ wf2b, bf16* __restrict__ gm)
{
    __shared__ __align__(16) unsigned short Bs[2][16*488];
    int tid = threadIdx.x, wave = tid>>6, lane = tid&63, m = lane&15, q = lane>>4;
    size_t pos0 = (size_t)blockIdx.x*64;
    size_t prow = (pos0 + wave*16 + m)*160;
    s8v a[15];
    #pragma unroll
    for (int kb = 0; kb < 15; ++kb){
        const bf16* src = (kb < 5) ? gT : (kb < 10 ? xhT : xwT);
        int kc = (kb - (kb < 5 ? 0 : (kb < 10 ? 5 : 10)))*32 + q*8;
        a[kb] = *(const s8v*)((const unsigned short*)src + prow + kc);
    }
    { const s8v* sp = (const s8v*)((const unsigned short*)wf2b);
      for (int c = tid; c < 960; c += 256){ int row = c/60, col = (c - row*60)*8;
          *(s8v*)&Bs[0][row*488 + col] = sp[c]; } }
    __syncthreads();
    for (int s = 0; s < 10; ++s){
        if (s+1 < 10){
            const s8v* sp = (const s8v*)((const unsigned short*)wf2b + (size_t)(s+1)*7680);
            for (int c = tid; c < 960; c += 256){ int row = c/60, col = (c - row*60)*8;
                *(s8v*)&Bs[(s+1)&1][row*488 + col] = sp[c]; }
        }
        f4v acc = {0.f,0.f,0.f,0.f};
        const unsigned short* Bp = &Bs[s&1][m*488 + q*8];
        #pragma unroll
        for (int kb = 0; kb < 15; ++kb) acc = MFMA(a[kb], *(const s8v*)(Bp + kb*32), acc);
        bf16* go = gm + (pos0 + wave*16 + q*4)*160 + s*16 + m;
        #pragma unroll
        for (int r = 0; r < 4; ++r) go[r*160] = f2b(acc[r]);
        __syncthreads();
    }
}

// ---------------- K78: fused channelMix (LN-folded fc1 + fc2 + residual) ----------------
// Per block: 32 positions. 4 waves = 2 row-tiles x 2 channel-halves.
// Phase A: stage x transposed (fp32). Phase B: y=x+gm, LN stats, y->bf16 LDS.
// Phase C: fc1 GEMM (LN folded), u -> LDS (never hits HBM). Phase D: fc2 GEMM,
// out = x + gm + fc2(u) + bias written straight from MFMA regs as float4 NCHW.
__global__ __launch_bounds__(256,3) void k78_mlp(const float* __restrict__ x,
    const bf16* __restrict__ gm,
    const bf16* __restrict__ wfc1g, const float* __restrict__ wgs, const float* __restrict__ wcb,
    const bf16* __restrict__ wfc2b, const float* __restrict__ bfc2,
    float* __restrict__ out)
{
    // LDS map (41,728 B -> 3 blocks/CU):
    //   [0, 31232)   : Us  ushort [32][488]  (phase C out / phase D in)
    //                  (phase A/B alias: Xs float [32][164] = 20,992 B)
    //   [31232,41472): As  ushort [32][160]  (y bf16)
    //   [41472,41600): rstd_s float[32]
    //   [41600,41728): mrs_s  float[32]
    __shared__ __align__(16) char lds[41728];
    float* Xs = (float*)lds;
    unsigned short* Us = (unsigned short*)lds;
    unsigned short* As = (unsigned short*)(lds + 31232);
    float* rstd_s = (float*)(lds + 41472);
    float* mrs_s  = (float*)(lds + 41600);

    int tid = threadIdx.x, wave = tid>>6, lane = tid&63, m = lane&15, q = lane>>4;
    int rt = wave&1, chh = wave>>1;
    int blk = blockIdx.x; int bb = blk/98; int hw0 = (blk - bb*98)*32;
    size_t pos0 = (size_t)bb*HWn + hw0;
    const float* xb = x + (size_t)bb*Cn*HWn + hw0;

    // ---- phase A: stage x transposed -> Xs[p][164]
    for (int idx = tid; idx < 160*32; idx += 256){
        int c = idx >> 5, p = idx & 31;
        Xs[p*164 + c] = xb[(size_t)c*HWn + p];
    }
    __syncthreads();

    // ---- phase B: y = x + gm; per-position mean/var (8 threads x 20 ch); As <- bf16(y)
    {
        int p = tid >> 3, q8 = tid & 7; int c0 = q8*20;
        const unsigned short* gp = (const unsigned short*)gm + (pos0 + p)*160 + c0;
        float y[20]; float s = 0.f, ss = 0.f;
        #pragma unroll
        for (int j = 0; j < 5; ++j){
            u4v gv = *(const u4v*)(gp + j*4);
            f4v xv = *(const f4v*)&Xs[p*164 + c0 + j*4];
            #pragma unroll
            for (int t = 0; t < 4; ++t){
                float vv = xv[t] + bits2f(gv[t]);
                y[j*4 + t] = vv; s += vv; ss += vv*vv;
            }
        }
        s += __shfl_xor(s, 1); ss += __shfl_xor(ss, 1);
        s += __shfl_xor(s, 2); ss += __shfl_xor(ss, 2);
        s += __shfl_xor(s, 4); ss += __shfl_xor(ss, 4);
        float mean = s * (1.f/160.f);
        float var  = ss * (1.f/160.f) - mean*mean;
        float rstd = rsqrtf(var + 1e-5f);
        #pragma unroll
        for (int j = 0; j < 5; ++j){
            u4v pk;
            #pragma unroll
            for (int t = 0; t < 4; ++t) pk[t] = f2bits(y[j*4 + t]);
            *(u4v*)&As[p*160 + c0 + j*4] = pk;
        }
        if (q8 == 0){ rstd_s[p] = rstd; mrs_s[p] = -mean*rstd; }
    }
    __syncthreads();   // As ready; all Xs reads done (Us writes below may overwrite Xs)

    // ---- phase C: fc1 (LN folded). wave (rt,chh): rows rt*16.., feature steps chh*15..+14
    {
        s8v a1[5];
        #pragma unroll
        for (int kb = 0; kb < 5; ++kb)
            a1[kb] = *(const s8v*)&As[(rt*16 + m)*160 + q*8 + kb*32];
        float rst[4], mrs[4];
        #pragma unroll
        for (int r = 0; r < 4; ++r){
            rst[r] = rstd_s[rt*16 + q*4 + r];
            mrs[r] = mrs_s [rt*16 + q*4 + r];
        }
        const unsigned short* W1 = (const unsigned short*)wfc1g + ((size_t)chh*15*16 + m)*160 + q*8;
        s8v b0[5], b1[5];
        #pragma unroll
        for (int kb = 0; kb < 5; ++kb) b0[kb] = *(const s8v*)(W1 + kb*32);
        #pragma unroll
        for (int s = 0; s < 15; ++s){
            if (s + 1 < 15){
                const unsigned short* Wn = W1 + (size_t)(s+1)*2560;
                #pragma unroll
                for (int kb = 0; kb < 5; ++kb) b1[kb] = *(const s8v*)(Wn + kb*32);
            }
            f4v acc = {0.f,0.f,0.f,0.f};
            #pragma unroll
            for (int kb = 0; kb < 5; ++kb) acc = MFMA(a1[kb], b0[kb], acc);
            int o = (chh*15 + s)*16 + m;
            float wg = wgs[o], wc = wcb[o];
            #pragma unroll
            for (int r = 0; r < 4; ++r){
                float v = acc[r]*rst[r] + mrs[r]*wg + wc;
                Us[(rt*16 + q*4 + r)*488 + o] = f2bits(gelu_f(v));
            }
            if (s + 1 < 15){
                #pragma unroll
                for (int kb = 0; kb < 5; ++kb) b0[kb] = b1[kb];
            }
        }
    }
    __syncthreads();   // u ready in LDS

    // ---- phase D: fc2 + residual. wave (rt,chh): rows rt*16.., out ch chh*80..+79
    {
        s8v a2[15];
        #pragma unroll
        for (int kb = 0; kb < 15; ++kb)
            a2[kb] = *(const s8v*)&Us[(rt*16 + m)*488 + q*8 + kb*32];
        #pragma unroll
        for (int s = 0; s < 5; ++s){
            int o = chh*80 + s*16 + m;
            const unsigned short* W2 = (const unsigned short*)wfc2b + (size_t)o*480 + q*8;
            s8v b2[15];
            #pragma unroll
            for (int kb = 0; kb < 15; ++kb) b2[kb] = *(const s8v*)(W2 + kb*32);
            f4v acc = {0.f,0.f,0.f,0.f};
            #pragma unroll
            for (int kb = 0; kb < 15; ++kb) acc = MFMA(a2[kb], b2[kb], acc);
            float bias = bfc2[o];
            const float* xp = x + (size_t)bb*Cn*HWn + (size_t)o*HWn + hw0 + rt*16 + q*4;
            f4v x4 = *(const f4v*)xp;
            const unsigned short* gmp = (const unsigned short*)gm + (pos0 + rt*16 + q*4)*160 + o;
            f4v o4;
            #pragma unroll
            for (int r = 0; r < 4; ++r)
                o4[r] = x4[r] + bits2f(gmp[(size_t)r*160]) + acc[r] + bias;
            float* op = out + (size_t)bb*Cn*HWn + (size_t)o*HWn + hw0 + rt*16 + q*4;
            *(f4v*)op = o4;
        }
    }
}

extern "C" void kernel_launch(void* const* d_in, const int* in_sizes, int n_in,
                              void* d_out, int out_size, void* d_ws, size_t ws_size,
                              hipStream_t stream)
{
    (void)in_sizes; (void)n_in; (void)out_size; (void)ws_size;
    const float* x     = (const float*)d_in[0];
    const float* bn1g  = (const float*)d_in[1];
    const float* bn1b  = (const float*)d_in[2];
    const float* bn1m  = (const float*)d_in[3];
    const float* bn1v  = (const float*)d_in[4];
    const float* wt    = (const float*)d_in[5];
    const float* bt    = (const float*)d_in[6];
    const float* wb    = (const float*)d_in[7];
    const float* bb    = (const float*)d_in[8];
    const float* wr    = (const float*)d_in[9];
    const float* br    = (const float*)d_in[10];
    const float* wl    = (const float*)d_in[11];
    const float* bl    = (const float*)d_in[12];
    const float* wc    = (const float*)d_in[13];
    const float* bc    = (const float*)d_in[14];
    const float* wf1   = (const float*)d_in[15];
    const float* bf1   = (const float*)d_in[16];
    const float* bn2g  = (const float*)d_in[17];
    const float* bn2b  = (const float*)d_in[18];
    const float* bn2m  = (const float*)d_in[19];
    const float* bn2v  = (const float*)d_in[20];
    const float* wph   = (const float*)d_in[21];
    const float* bph   = (const float*)d_in[22];
    const float* wpw   = (const float*)d_in[23];
    const float* bpw   = (const float*)d_in[24];
    const float* wf2   = (const float*)d_in[25];
    const float* lng   = (const float*)d_in[26];
    const float* lnb   = (const float*)d_in[27];
    const float* wfc1  = (const float*)d_in[28];
    const float* bfc1  = (const float*)d_in[29];
    const float* wfc2  = (const float*)d_in[30];
    const float* bfc2v = (const float*)d_in[31];
    float* outp = (float*)d_out;

    // workspace layout (bytes); bf16 [Pn][160] buffer = 32,112,640 B
    const size_t PC2 = (size_t)Pn*160*2;
    char* ws = (char*)d_ws;
    bf16* hT   = (bf16*)(ws + 0*PC2);
    bf16* y5T  = (bf16*)(ws + 1*PC2);
    bf16* gT   = (bf16*)(ws + 2*PC2);
    bf16* xhT  = (bf16*)(ws + 3*PC2);
    bf16* xwT  = (bf16*)(ws + 4*PC2);
    bf16* gm   = (bf16*)(ws + 5*PC2);
    char* wsw  = ws + 6*PC2;                       // weights @ 192,675,840
    bf16*  wcat  = (bf16*)(wsw + 0);
    bf16*  wf1b  = (bf16*)(wsw + 51200);
    bf16*  wf2b  = (bf16*)(wsw + 102400);
    bf16*  wfc1g = (bf16*)(wsw + 256000);
    bf16*  wfc2b = (bf16*)(wsw + 409600);
    bf16*  wphb  = (bf16*)(wsw + 563200);
    bf16*  wpwb  = (bf16*)(wsw + 571392);
    float* bcat  = (float*)(wsw + 579584);
    float* epsv  = (float*)(wsw + 580224);
    float* eptv  = (float*)(wsw + 580864);
    float* wgs   = (float*)(wsw + 581504);
    float* wcb   = (float*)(wsw + 583424);

    const int GP = Pn/64;     // 1568
    const int GS = Bn*56;     // 1792
    const int GF = Pn/32;     // 3136

    k0_prep<<<1136, 256, 0, stream>>>(wt, wb, wr, wl, wc, bt, bb, br, bl, bc,
                                      wf1, bf1, bn2g, bn2b, bn2m, bn2v,
                                      wf2, wfc1, wfc2, wph, wpw,
                                      lng, lnb, bfc1,
                                      wcat, wf1b, wf2b, wfc1g, wfc2b, wphb, wpwb,
                                      bcat, epsv, eptv, wgs, wcb);
    k1_bn_gelu_tr<<<GP, 256, 0, stream>>>(x, bn1g, bn1b, bn1m, bn1v, hT);
    k2_conv5     <<<GP, 256, 0, stream>>>(hT, wcat, bcat, y5T);
    k3_wf1       <<<GP, 256, 0, stream>>>(y5T, wf1b, epsv, eptv, gT);
    k4_projh     <<<GS, 256, 0, stream>>>(gT, wphb, bph, xhT);
    k5_projw     <<<GS, 256, 0, stream>>>(gT, wpwb, bpw, xwT);
    k6_wf2       <<<GP, 256, 0, stream>>>(gT, xhT, xwT, wf2b, gm);
    k78_mlp      <<<GF, 256, 0, stream>>>(x, gm, wfc1g, wgs, wcb, wfc2b, bfc2v, outp);
}